// Round 6
// baseline (114.410 us; speedup 1.0000x reference)
//
#include <hip/hip_runtime.h>
#include <hip/hip_bf16.h>

#define B_DIM  8
#define N_DIM  2048
#define CIN    256
#define COUT   256
#define F_DIM  8
#define EPS    1e-4f
#define MTOT   (B_DIM * N_DIM)        // 16384 global rows

using short8 = __attribute__((ext_vector_type(8))) short;
using f32x4  = __attribute__((ext_vector_type(4))) float;

__device__ __forceinline__ unsigned short f2bf(float f) {
    union { float f; unsigned u; } x; x.f = f;
    unsigned r = x.u + 0x7FFFu + ((x.u >> 16) & 1u);   // RNE
    return (unsigned short)(r >> 16);
}
__device__ __forceinline__ unsigned fbits(float f) {
    union { float f; unsigned u; } x; x.f = f;
    return x.u;
}

// ---------------- Kernel 1: W[k,i] = sum_f pw[f] * filters[f,k,i]  (bf16 out)
__global__ __launch_bounds__(256) void wb_build(const float* __restrict__ filters,
                                                const float* __restrict__ proj_w,
                                                unsigned short* __restrict__ Wb) {
    int gid = blockIdx.x * 256 + threadIdx.x;      // = k*256 + i
    float acc = 0.f;
#pragma unroll
    for (int f = 0; f < F_DIM; ++f)
        acc += proj_w[f] * filters[f * (COUT * CIN) + gid];
    Wb[gid] = f2bf(acc);
}

// ---------------- Kernel 2: xpT[c, g] = W[c,:]·nf[g,:] + bias   (bf16, TRANSPOSED)
// A = W rows (bf16 direct), B = nf rows (fp32 -> bf16 RNE). D row-dim = c, col-dim = g.
__global__ __launch_bounds__(256) void xpT_gemm(const float* __restrict__ nf,
                                                const unsigned short* __restrict__ Wb,
                                                const float* __restrict__ proj_b,
                                                unsigned short* __restrict__ xpT) {
    const int tid  = threadIdx.x;
    const int lane = tid & 63;
    const int wv   = tid >> 6;                      // 0..3
    const int lrow = lane & 15;
    const int kgrp = lane >> 4;                     // 0..3
    const int m0   = (blockIdx.x & 3) * 64;         // c-tile base (M=256)
    const int n0   = (blockIdx.x >> 2) * 256 + wv * 64;  // g-tile base (N=16384)
    const float bias = proj_b[0];

    f32x4 acc[4][4];
#pragma unroll
    for (int a = 0; a < 4; ++a)
#pragma unroll
        for (int b = 0; b < 4; ++b)
            acc[a][b] = (f32x4){0.f, 0.f, 0.f, 0.f};

#pragma unroll
    for (int ks = 0; ks < 8; ++ks) {                // K = 8 * 32
        const int klane = ks * 32 + kgrp * 8;
        short8 af[4], bfr[4];
#pragma unroll
        for (int fm = 0; fm < 4; ++fm)              // A = W rows, bf16 direct
            af[fm] = *(const short8*)&Wb[(size_t)(m0 + fm * 16 + lrow) * CIN + klane];
#pragma unroll
        for (int fn = 0; fn < 4; ++fn) {            // B = nf rows, cvt RNE
            const float* bp = nf + (size_t)(n0 + fn * 16 + lrow) * CIN + klane;
            float4 b0 = *(const float4*)bp;
            float4 b1 = *(const float4*)(bp + 4);
            short8 t;
            t[0] = (short)f2bf(b0.x); t[1] = (short)f2bf(b0.y);
            t[2] = (short)f2bf(b0.z); t[3] = (short)f2bf(b0.w);
            t[4] = (short)f2bf(b1.x); t[5] = (short)f2bf(b1.y);
            t[6] = (short)f2bf(b1.z); t[7] = (short)f2bf(b1.w);
            bfr[fn] = t;
        }
#pragma unroll
        for (int fm = 0; fm < 4; ++fm)
#pragma unroll
            for (int fn = 0; fn < 4; ++fn)
                acc[fm][fn] = __builtin_amdgcn_mfma_f32_16x16x32_bf16(
                    af[fm], bfr[fn], acc[fm][fn], 0, 0, 0);
    }

    // D: row (c) = m0+fm*16+kgrp*4+r, col (g) = n0+fn*16+lrow
#pragma unroll
    for (int fm = 0; fm < 4; ++fm)
#pragma unroll
        for (int fn = 0; fn < 4; ++fn) {
            const int g = n0 + fn * 16 + lrow;
#pragma unroll
            for (int r = 0; r < 4; ++r) {
                const int c = m0 + fm * 16 + kgrp * 4 + r;
                xpT[(size_t)c * MTOT + g] = f2bf(acc[fm][fn][r] + bias);
            }
        }
}

// ---------------- Kernel 3: out[b] = (adj[b] @ x'[b]) / (deg + eps), dense MFMA.
// adj in {0,1} exactly -> bf16 truncation exact. deg = rowsum(adj) accumulated
// from the raw fp32 A during conversion (free). 1-deep register prefetch.
#define COMPUTE_STEP(AR, BR)                                                     \
    {                                                                            \
        short8 af_[4];                                                           \
        _Pragma("unroll")                                                        \
        for (int fm = 0; fm < 4; ++fm) {                                         \
            float4 x0 = AR[fm][0], x1 = AR[fm][1];                               \
            deg[fm] += x0.x + x0.y + x0.z + x0.w + x1.x + x1.y + x1.z + x1.w;    \
            short8 t;                                                            \
            t[0] = (short)(fbits(x0.x) >> 16); t[1] = (short)(fbits(x0.y) >> 16);\
            t[2] = (short)(fbits(x0.z) >> 16); t[3] = (short)(fbits(x0.w) >> 16);\
            t[4] = (short)(fbits(x1.x) >> 16); t[5] = (short)(fbits(x1.y) >> 16);\
            t[6] = (short)(fbits(x1.z) >> 16); t[7] = (short)(fbits(x1.w) >> 16);\
            af_[fm] = t;                                                         \
        }                                                                        \
        _Pragma("unroll")                                                        \
        for (int fm = 0; fm < 4; ++fm)                                           \
            _Pragma("unroll")                                                    \
            for (int fn = 0; fn < 4; ++fn)                                       \
                acc[fm][fn] = __builtin_amdgcn_mfma_f32_16x16x32_bf16(           \
                    af_[fm], BR[fn], acc[fm][fn], 0, 0, 0);                      \
    }

__global__ __launch_bounds__(256) void adj_gemm(const float* __restrict__ adj,
                                                const unsigned short* __restrict__ xpT,
                                                float* __restrict__ out) {
    const int tid  = threadIdx.x;
    const int lane = tid & 63;
    const int wv   = tid >> 6;
    const int lrow = lane & 15;
    const int kgrp = lane >> 4;
    const int bid  = blockIdx.x;
    const int b    = bid & 7;                 // batch == XCD (heuristic)
    const int row0 = (bid >> 3) * 64;         // row tile within batch
    const int n0   = wv * 64;                 // wave's 64 output channels

    const float* aptr[4];
#pragma unroll
    for (int fm = 0; fm < 4; ++fm)
        aptr[fm] = adj + ((size_t)b * N_DIM + row0 + fm * 16 + lrow) * N_DIM + kgrp * 8;
    const unsigned short* bptr[4];
#pragma unroll
    for (int fn = 0; fn < 4; ++fn)
        bptr[fn] = xpT + (size_t)(n0 + fn * 16 + lrow) * MTOT + b * N_DIM + kgrp * 8;

    f32x4 acc[4][4];
#pragma unroll
    for (int a = 0; a < 4; ++a)
#pragma unroll
        for (int c = 0; c < 4; ++c)
            acc[a][c] = (f32x4){0.f, 0.f, 0.f, 0.f};
    float deg[4] = {0.f, 0.f, 0.f, 0.f};

    // preload K-step 0
    float4 A0[4][2], A1[4][2];
    short8 B0[4], B1[4];
#pragma unroll
    for (int fm = 0; fm < 4; ++fm) {
        A0[fm][0] = *(const float4*)(aptr[fm]);
        A0[fm][1] = *(const float4*)(aptr[fm] + 4);
    }
#pragma unroll
    for (int fn = 0; fn < 4; ++fn)
        B0[fn] = *(const short8*)(bptr[fn]);

#pragma unroll 1
    for (int t = 0; t < 32; ++t) {            // 64 K-steps, 2 per iter
        const int j1 = t * 64 + 32;
#pragma unroll
        for (int fm = 0; fm < 4; ++fm) {
            A1[fm][0] = *(const float4*)(aptr[fm] + j1);
            A1[fm][1] = *(const float4*)(aptr[fm] + j1 + 4);
        }
#pragma unroll
        for (int fn = 0; fn < 4; ++fn)
            B1[fn] = *(const short8*)(bptr[fn] + j1);

        COMPUTE_STEP(A0, B0);

        const int j2 = (t < 31) ? t * 64 + 64 : 0;   // phantom last prefetch (DCE'd or harmless)
#pragma unroll
        for (int fm = 0; fm < 4; ++fm) {
            A0[fm][0] = *(const float4*)(aptr[fm] + j2);
            A0[fm][1] = *(const float4*)(aptr[fm] + j2 + 4);
        }
#pragma unroll
        for (int fn = 0; fn < 4; ++fn)
            B0[fn] = *(const short8*)(bptr[fn] + j2);

        COMPUTE_STEP(A1, B1);
    }

    // deg: sum the 4 kgrp partials (lanes lrow+0/16/32/48) -> full rowsum, replicated
#pragma unroll
    for (int fm = 0; fm < 4; ++fm) {
        float d = deg[fm];
        d += __shfl_xor(d, 16, 64);
        d += __shfl_xor(d, 32, 64);
        deg[fm] = d;
    }

    // D: row = row0+fm*16+kgrp*4+r, col = n0+fn*16+lrow
#pragma unroll
    for (int fm = 0; fm < 4; ++fm)
#pragma unroll
        for (int r = 0; r < 4; ++r) {
            const float dv  = __shfl(deg[fm], kgrp * 4 + r, 64); // lane kgrp*4+r holds row's deg
            const float inv = __builtin_amdgcn_rcpf(dv + EPS);
            const int grow  = b * N_DIM + row0 + fm * 16 + kgrp * 4 + r;
#pragma unroll
            for (int fn = 0; fn < 4; ++fn)
                out[(size_t)grow * COUT + n0 + fn * 16 + lrow] = acc[fm][fn][r] * inv;
        }
}

extern "C" void kernel_launch(void* const* d_in, const int* in_sizes, int n_in,
                              void* d_out, int out_size, void* d_ws, size_t ws_size,
                              hipStream_t stream) {
    const float* nf      = (const float*)d_in[0];
    const float* adj     = (const float*)d_in[1];
    const float* filters = (const float*)d_in[2];
    const float* proj_w  = (const float*)d_in[3];
    const float* proj_b  = (const float*)d_in[4];
    float* out = (float*)d_out;

    unsigned short* Wb  = (unsigned short*)d_ws;                            // 128 KB
    unsigned short* xpT = (unsigned short*)((char*)d_ws + COUT * CIN * 2);  // 8 MB, [256][16384]

    wb_build<<<(COUT * CIN) / 256, 256, 0, stream>>>(filters, proj_w, Wb);
    xpT_gemm<<<256, 256, 0, stream>>>(nf, Wb, proj_b, xpT);
    adj_gemm<<<256, 256, 0, stream>>>(adj, xpT, out);
}